// Round 1
// baseline (332.394 us; speedup 1.0000x reference)
//
#include <hip/hip_runtime.h>

// Problem constants
#define NB 128
#define NC 256
#define HX 31
#define WX 31
#define HZ 7
#define WZ 7
#define HC 25          // corr spatial (31-7+1)
#define WC 25
#define HO 23          // head output spatial (25-3+1)
#define WO 23
#define CHUNKS 4       // channel chunks per batch item
#define CPB (NC / CHUNKS)   // 64 channels per block
#define GRP 10              // channels processed per group iteration
#define XROW 35             // padded LDS row stride for x (breaks 5-way diagonal bank conflict)
#define XCH (HX * XROW)     // 1085 floats per channel of x in LDS
#define ZCH 52              // padded z stride (16B-aligned rows for b128 reads)
#define CCH (HC * WC)       // 625

#define HEAT_SZ (NB * HO * WO)       // 67712
#define REG_SZ  (NB * 4 * HO * WO)   // 270848
#define OUT_TOTAL (HEAT_SZ + REG_SZ) // 338560

// Writes bias into d_out (harness poisons d_out with 0xAA before every launch).
__global__ void init_out_kernel(float* __restrict__ out,
                                const float* __restrict__ heat_b,
                                const float* __restrict__ reg_b) {
    int i = blockIdx.x * 256 + threadIdx.x;
    if (i >= OUT_TOTAL) return;
    if (i < HEAT_SZ) {
        out[i] = heat_b[0];
    } else {
        int j = i - HEAT_SZ;
        int o = (j / (HO * WO)) & 3;
        out[i] = reg_b[o];
    }
}

// Fused depthwise xcorr + dual 3x3 conv heads.
// Block = (n, chunk): accumulates 64 channels' contribution, atomicAdd to out.
__launch_bounds__(256, 2)
__global__ void fused_head_kernel(const float* __restrict__ xf,
                                  const float* __restrict__ zf,
                                  const float* __restrict__ hw,
                                  const float* __restrict__ rw,
                                  float* __restrict__ out) {
    __shared__ float xs[GRP * XCH];                       // 43.4 KB
    __shared__ __align__(16) float zs[GRP * ZCH];         // 2.1 KB
    __shared__ float cs[GRP * CCH];                       // 25 KB

    const int tid = threadIdx.x;
    const int bid = blockIdx.x;
    const int n = bid >> 2;
    const int chunk = bid & 3;
    const int cbase = chunk * CPB;

    // corr-phase mapping: 25 threads per channel, each owns a 5x5 corr tile
    const int cl_corr = tid / 25;          // channel-in-group (>= G -> idle)
    const int tt = tid % 25;
    const int tr = tt / 5, tc = tt % 5;
    const int i0 = tr * 5, j0 = tc * 5;

    // conv-phase mapping: thread owns pixels tid, tid+256, (tid+512 if tid<17)
    const int p0 = tid;
    const int p1 = tid + 256;
    const int p2 = tid + 512;
    const int oy0 = p0 / 23, ox0 = p0 - oy0 * 23;
    const int oy1 = p1 / 23, ox1 = p1 - oy1 * 23;
    const int oy2 = p2 / 23, ox2 = p2 - oy2 * 23;  // valid only if tid<17
    const int off0 = oy0 * WC + ox0;
    const int off1 = oy1 * WC + ox1;
    const int off2 = (tid < 17) ? (oy2 * WC + ox2) : 0;

    float accH0 = 0.f, accH1 = 0.f, accH2 = 0.f;
    float accR0[4] = {0.f, 0.f, 0.f, 0.f};
    float accR1[4] = {0.f, 0.f, 0.f, 0.f};
    float accR2[4] = {0.f, 0.f, 0.f, 0.f};

    const float* xn = xf + (size_t)(n * NC + cbase) * (HX * WX);
    const float* zn = zf + (size_t)(n * NC + cbase) * (HZ * WZ);

    for (int g0 = 0; g0 < CPB; g0 += GRP) {
        const int G = (CPB - g0) < GRP ? (CPB - g0) : GRP;  // 10,...,10,4

        // ---- stage x (global -> LDS, padded row stride) ----
        for (int cl = 0; cl < G; ++cl) {
            const float* src = xn + (size_t)(g0 + cl) * (HX * WX);
            float* dst = xs + cl * XCH;
            for (int k = tid; k < HX * WX; k += 256) {
                int r = k / WX;
                int col = k - r * WX;
                dst[r * XROW + col] = src[k];
            }
        }
        // ---- stage z (padded to 52 for aligned b128 reads) ----
        {
            const float* src = zn + (size_t)g0 * (HZ * WZ);
            for (int k = tid; k < G * 49; k += 256) {
                int cl = k / 49;
                int q = k - cl * 49;
                zs[cl * ZCH + q] = src[k];
            }
        }
        __syncthreads();

        // ---- depthwise xcorr: each thread computes a 5x5 corr tile ----
        if (cl_corr < G) {
            float zr[52];
            const float4* zp4 = (const float4*)(zs + cl_corr * ZCH);
            #pragma unroll
            for (int q = 0; q < 13; ++q) {
                float4 v = zp4[q];
                zr[q * 4 + 0] = v.x; zr[q * 4 + 1] = v.y;
                zr[q * 4 + 2] = v.z; zr[q * 4 + 3] = v.w;
            }
            float acc[5][5];
            #pragma unroll
            for (int r = 0; r < 5; ++r) {
                #pragma unroll
                for (int c = 0; c < 5; ++c) acc[r][c] = 0.f;
            }
            const float* xb = xs + cl_corr * XCH + i0 * XROW + j0;
            #pragma unroll
            for (int a = 0; a < 11; ++a) {
                float xr[11];
                #pragma unroll
                for (int k = 0; k < 11; ++k) xr[k] = xb[a * XROW + k];
                #pragma unroll
                for (int r = 0; r < 5; ++r) {
                    const int u = a - r;
                    if (u >= 0 && u < 7) {
                        #pragma unroll
                        for (int v = 0; v < 7; ++v) {
                            const float zv = zr[u * 7 + v];
                            #pragma unroll
                            for (int c = 0; c < 5; ++c)
                                acc[r][c] = fmaf(zv, xr[c + v], acc[r][c]);
                        }
                    }
                }
            }
            float* cb = cs + cl_corr * CCH + i0 * WC + j0;
            #pragma unroll
            for (int r = 0; r < 5; ++r) {
                #pragma unroll
                for (int c = 0; c < 5; ++c) cb[r * WC + c] = acc[r][c];
            }
        }
        __syncthreads();

        // ---- conv heads: accumulate over this group's channels ----
        for (int cl = 0; cl < G; ++cl) {
            const int c = cbase + g0 + cl;
            // block-uniform addresses -> scalar (s_load) weight fetches
            const float* wh = hw + c * 9;
            const float* wr0p = rw + (size_t)(0 * NC + c) * 9;
            const float* wr1p = rw + (size_t)(1 * NC + c) * 9;
            const float* wr2p = rw + (size_t)(2 * NC + c) * 9;
            const float* wr3p = rw + (size_t)(3 * NC + c) * 9;
            float wv[45];
            #pragma unroll
            for (int k = 0; k < 9; ++k) {
                wv[k]      = wh[k];
                wv[9 + k]  = wr0p[k];
                wv[18 + k] = wr1p[k];
                wv[27 + k] = wr2p[k];
                wv[36 + k] = wr3p[k];
            }
            const float* cc = cs + cl * CCH;

            {   // pixel p0
                const float* base = cc + off0;
                #pragma unroll
                for (int dy = 0; dy < 3; ++dy) {
                    #pragma unroll
                    for (int dx = 0; dx < 3; ++dx) {
                        const float cv = base[dy * WC + dx];
                        const int k = dy * 3 + dx;
                        accH0 = fmaf(cv, wv[k], accH0);
                        accR0[0] = fmaf(cv, wv[9 + k],  accR0[0]);
                        accR0[1] = fmaf(cv, wv[18 + k], accR0[1]);
                        accR0[2] = fmaf(cv, wv[27 + k], accR0[2]);
                        accR0[3] = fmaf(cv, wv[36 + k], accR0[3]);
                    }
                }
            }
            {   // pixel p1
                const float* base = cc + off1;
                #pragma unroll
                for (int dy = 0; dy < 3; ++dy) {
                    #pragma unroll
                    for (int dx = 0; dx < 3; ++dx) {
                        const float cv = base[dy * WC + dx];
                        const int k = dy * 3 + dx;
                        accH1 = fmaf(cv, wv[k], accH1);
                        accR1[0] = fmaf(cv, wv[9 + k],  accR1[0]);
                        accR1[1] = fmaf(cv, wv[18 + k], accR1[1]);
                        accR1[2] = fmaf(cv, wv[27 + k], accR1[2]);
                        accR1[3] = fmaf(cv, wv[36 + k], accR1[3]);
                    }
                }
            }
            if (tid < 17) {   // pixel p2
                const float* base = cc + off2;
                #pragma unroll
                for (int dy = 0; dy < 3; ++dy) {
                    #pragma unroll
                    for (int dx = 0; dx < 3; ++dx) {
                        const float cv = base[dy * WC + dx];
                        const int k = dy * 3 + dx;
                        accH2 = fmaf(cv, wv[k], accH2);
                        accR2[0] = fmaf(cv, wv[9 + k],  accR2[0]);
                        accR2[1] = fmaf(cv, wv[18 + k], accR2[1]);
                        accR2[2] = fmaf(cv, wv[27 + k], accR2[2]);
                        accR2[3] = fmaf(cv, wv[36 + k], accR2[3]);
                    }
                }
            }
        }
        __syncthreads();
    }

    // ---- epilogue: atomic accumulate into out (bias pre-written) ----
    float* outH = out;
    float* outR = out + HEAT_SZ;
    const int hbase = n * (HO * WO);
    const int rbase = n * 4 * (HO * WO);

    atomicAdd(&outH[hbase + p0], accH0);
    #pragma unroll
    for (int o = 0; o < 4; ++o)
        atomicAdd(&outR[rbase + o * (HO * WO) + p0], accR0[o]);

    atomicAdd(&outH[hbase + p1], accH1);
    #pragma unroll
    for (int o = 0; o < 4; ++o)
        atomicAdd(&outR[rbase + o * (HO * WO) + p1], accR1[o]);

    if (tid < 17) {
        atomicAdd(&outH[hbase + p2], accH2);
        #pragma unroll
        for (int o = 0; o < 4; ++o)
            atomicAdd(&outR[rbase + o * (HO * WO) + p2], accR2[o]);
    }
}

extern "C" void kernel_launch(void* const* d_in, const int* in_sizes, int n_in,
                              void* d_out, int out_size, void* d_ws, size_t ws_size,
                              hipStream_t stream) {
    const float* x_f    = (const float*)d_in[0];
    const float* z_f    = (const float*)d_in[1];
    const float* heat_w = (const float*)d_in[2];
    const float* heat_b = (const float*)d_in[3];
    const float* reg_w  = (const float*)d_in[4];
    const float* reg_b  = (const float*)d_in[5];
    float* out = (float*)d_out;

    // 1) write biases into the (poisoned) output buffer
    init_out_kernel<<<(OUT_TOTAL + 255) / 256, 256, 0, stream>>>(out, heat_b, reg_b);

    // 2) fused xcorr + conv heads, atomic accumulation
    fused_head_kernel<<<NB * CHUNKS, 256, 0, stream>>>(x_f, z_f, heat_w, reg_w, out);
}